// Round 3
// baseline (128.317 us; speedup 1.0000x reference)
//
#include <hip/hip_runtime.h>
#include <hip/hip_cooperative_groups.h>

namespace cg = cooperative_groups;

#define H 512
#define W 512
#define N (H * W)
#define INF_SQ 524289.0f  // H*H + W*W + 1, matches reference INF

__global__ __launch_bounds__(512, 4)
void edt_fused_k(const float* __restrict__ masks, float* __restrict__ out,
                 float* __restrict__ d1, float* __restrict__ colmax,
                 float* __restrict__ rowmax) {
    cg::grid_group grid = cg::this_grid();
    const int b = blockIdx.x;
    const int t = threadIdx.x;

    __shared__ int A[H];       // prefix max of zero-indices
    __shared__ int B[H];       // suffix min of zero-indices
    __shared__ float sr[W];    // row of d1 (phase 2)
    __shared__ float red[8];
    __shared__ float smc[8], smr[8];

    // ---- Phase 1: column pass (block b = column c) ----
    {
        const int c = b;
        const float v = masks[t * W + c];
        const bool z = (v == 0.0f);
        A[t] = z ? t : -100000;
        B[t] = z ? t : 100000;

        // per-column max of masks
        float m = v;
        for (int off = 32; off > 0; off >>= 1) m = fmaxf(m, __shfl_down(m, off, 64));
        if ((t & 63) == 0) red[t >> 6] = m;
        __syncthreads();

        // Hillis-Steele prefix-max (A) / suffix-min (B)
        for (int off = 1; off < H; off <<= 1) {
            int a = (t >= off) ? A[t - off] : -100000;
            int bb = (t + off < H) ? B[t + off] : 100000;
            __syncthreads();
            A[t] = max(A[t], a);
            B[t] = min(B[t], bb);
            __syncthreads();
        }
        const int nd = min(t - A[t], B[t] - t);
        d1[t * W + c] = (nd <= H - 1) ? (float)(nd * nd) : INF_SQ;

        if (t == 0) {
            float q = red[0];
            for (int i = 1; i < 8; i++) q = fmaxf(q, red[i]);
            colmax[c] = q;
        }
    }

    grid.sync();

    // ---- Phase 2: row pass (block b = row h); dis kept in register ----
    float dreg;
    {
        const int h = b;
        const int k = t;
        sr[k] = d1[h * W + k];
        __syncthreads();

        // exact windowed min-plus: any l with (k-l)^2 > ub can't beat l=k
        const float ub = sr[k];
        int R = (int)ceilf(sqrtf(ub));
        for (int off = 32; off > 0; off >>= 1) R = max(R, __shfl_down(R, off, 64));
        R = __shfl(R, 0, 64);           // wave-uniform
        if (R > W) R = W;               // degenerate (no zero in column) safety

        float m = ub;                   // l = k candidate
        for (int o = 1; o <= R; ++o) {
            const float oo = (float)o * (float)o;
            const int lm = k - o, lp = k + o;
            const float a = (lm >= 0) ? sr[lm] : 1e30f;
            const float c2 = (lp < W) ? sr[lp] : 1e30f;
            m = fminf(m, oo + fminf(a, c2));
        }
        dreg = sqrtf(m);

        float r = dreg;
        for (int off = 32; off > 0; off >>= 1) r = fmaxf(r, __shfl_down(r, off, 64));
        __syncthreads();                // sr no longer needed; reuse red safely
        if ((k & 63) == 0) red[k >> 6] = r;
        __syncthreads();
        if (k == 0) {
            for (int i = 1; i < 8; i++) r = fmaxf(r, red[i]);
            rowmax[h] = r;
        }
    }

    grid.sync();

    // ---- Phase 3: redundant global-max reduce + normalize (block b = row h) ----
    {
        const int h = b;
        float cm = colmax[t];
        float rm = rowmax[t];
        for (int off = 32; off > 0; off >>= 1) {
            cm = fmaxf(cm, __shfl_down(cm, off, 64));
            rm = fmaxf(rm, __shfl_down(rm, off, 64));
        }
        if ((t & 63) == 0) { smc[t >> 6] = cm; smr[t >> 6] = rm; }
        __syncthreads();
        if (t == 0) {
            for (int i = 1; i < 8; i++) { cm = fmaxf(cm, smc[i]); rm = fmaxf(rm, smr[i]); }
            smc[0] = cm; smr[0] = rm;
        }
        __syncthreads();
        const float maxm = smc[0];
        const float maxd = smr[0];

        const int i = h * W + t;
        const float sk = dreg / maxd;
        out[i] = sk;                    // skeleton
        out[N + i] = masks[i] / maxm - sk;  // boundary
    }
}

extern "C" void kernel_launch(void* const* d_in, const int* in_sizes, int n_in,
                              void* d_out, int out_size, void* d_ws, size_t ws_size,
                              hipStream_t stream) {
    const float* masks = (const float*)d_in[0];
    float* out = (float*)d_out;
    float* d1 = (float*)d_ws;       // N floats
    float* colmax = d1 + N;         // W floats
    float* rowmax = colmax + W;     // H floats

    void* args[] = {(void*)&masks, (void*)&out, (void*)&d1, (void*)&colmax, (void*)&rowmax};
    hipLaunchCooperativeKernel((void*)edt_fused_k, dim3(H), dim3(512), args, 0, stream);
}

// Round 5
// 16.801 us; speedup vs baseline: 7.6374x; 7.6374x over previous
//
#include <hip/hip_runtime.h>

#define H 512
#define W 512
#define N (H * W)
#define INF_SQ 524289.0f  // H*H + W*W + 1, matches reference INF

// K1: one block per column c. Nearest-zero via per-wave ballot masks.
//   d1[i][c] = nd^2 (nd = distance to nearest zero in column), INF_SQ if none.
//   colmax[c] = max over rows of masks[.][c].
__global__ __launch_bounds__(512)
void colscan_k(const float* __restrict__ masks, float* __restrict__ d1,
               float* __restrict__ colmax) {
    const int c = blockIdx.x;
    const int t = threadIdx.x;      // row
    const int w = t >> 6, lane = t & 63;

    __shared__ unsigned long long smask[8];  // zero-pixel bitmask per wave
    __shared__ float red[8];

    const float v = masks[t * W + c];
    const unsigned long long bal = __ballot(v == 0.0f);
    if (lane == 0) smask[w] = bal;

    float m = v;
    for (int off = 32; off > 0; off >>= 1) m = fmaxf(m, __shfl_down(m, off, 64));
    if (lane == 0) red[w] = m;
    __syncthreads();

    // nearest zero at index <= t
    int prev = -100000;
    {
        const unsigned long long bel = smask[w] << (63 - lane);  // bit t at pos 63
        if (bel) prev = t - __clzll(bel);
        else {
            for (int ww = w - 1; ww >= 0; --ww)
                if (smask[ww]) { prev = (ww << 6) + 63 - __clzll(smask[ww]); break; }
        }
    }
    // nearest zero at index >= t
    int nxt = 100000;
    {
        const unsigned long long abv = smask[w] >> lane;         // bit t at pos 0
        if (abv) nxt = t + (__ffsll((unsigned long long)abv) - 1);
        else {
            for (int ww = w + 1; ww < 8; ++ww)
                if (smask[ww]) { nxt = (ww << 6) + (__ffsll((unsigned long long)smask[ww]) - 1); break; }
        }
    }
    const int nd = min(t - prev, nxt - t);
    d1[t * W + c] = (nd <= H - 1) ? (float)(nd * nd) : INF_SQ;

    if (t == 0) {
        float q = red[0];
        for (int i = 1; i < 8; i++) q = fmaxf(q, red[i]);
        colmax[c] = q;
    }
}

// K2: one block per row h. Exact WINDOWED min-plus:
//   ub = d1[h][k] (candidate l=k); any l with (k-l)^2 > ub cannot win,
//   so only offsets o <= R = ceil(sqrt(ub)) matter. R wave-maxed for uniformity.
__global__ __launch_bounds__(512)
void rowpass_k(const float* __restrict__ d1, float* __restrict__ dis,
               float* __restrict__ rowmax) {
    const int h = blockIdx.x;
    const int k = threadIdx.x;      // col

    __shared__ float sr[W];
    __shared__ float sm[8];
    sr[k] = d1[h * W + k];
    __syncthreads();

    const float ub = sr[k];
    int R = (int)ceilf(sqrtf(ub));
    for (int off = 32; off > 0; off >>= 1) R = max(R, __shfl_down(R, off, 64));
    R = __shfl(R, 0, 64);           // wave-uniform window
    if (R > W - 1) R = W - 1;       // degenerate (no zero anywhere) safety

    float m = ub;
    for (int o = 1; o <= R; ++o) {
        const float oo = (float)o * (float)o;
        const int lm = k - o, lp = k + o;
        const float a = (lm >= 0) ? sr[lm] : 1e30f;
        const float b = (lp < W) ? sr[lp] : 1e30f;
        m = fminf(m, oo + fminf(a, b));
    }
    const float d = sqrtf(m);
    dis[h * W + k] = d;

    float r = d;
    for (int off = 32; off > 0; off >>= 1) r = fmaxf(r, __shfl_down(r, off, 64));
    if ((k & 63) == 0) sm[k >> 6] = r;
    __syncthreads();
    if (k == 0) {
        for (int i = 1; i < 8; i++) r = fmaxf(r, sm[i]);
        rowmax[h] = r;
    }
}

// K3: every block redundantly reduces the 512+512 partial maxima, then
// normalizes its row.
__global__ __launch_bounds__(512)
void finalize_k(const float* __restrict__ masks,
                const float* __restrict__ colmax,
                const float* __restrict__ rowmax,
                float* __restrict__ out) {
    const int h = blockIdx.x;
    const int t = threadIdx.x;

    __shared__ float smc[8], smr[8];
    float cm = colmax[t];
    float rm = rowmax[t];
    for (int off = 32; off > 0; off >>= 1) {
        cm = fmaxf(cm, __shfl_down(cm, off, 64));
        rm = fmaxf(rm, __shfl_down(rm, off, 64));
    }
    if ((t & 63) == 0) { smc[t >> 6] = cm; smr[t >> 6] = rm; }
    __syncthreads();
    if (t == 0) {
        for (int i = 1; i < 8; i++) { cm = fmaxf(cm, smc[i]); rm = fmaxf(rm, smr[i]); }
        smc[0] = cm; smr[0] = rm;
    }
    __syncthreads();
    const float maxm = smc[0];
    const float maxd = smr[0];

    const int i = h * W + t;
    const float d = out[i];         // dis written by rowpass_k
    const float sk = d / maxd;
    out[i] = sk;                    // skeleton
    out[N + i] = masks[i] / maxm - sk;  // boundary
}

extern "C" void kernel_launch(void* const* d_in, const int* in_sizes, int n_in,
                              void* d_out, int out_size, void* d_ws, size_t ws_size,
                              hipStream_t stream) {
    const float* masks = (const float*)d_in[0];
    float* out = (float*)d_out;
    float* d1 = (float*)d_ws;       // N floats
    float* colmax = d1 + N;         // W floats
    float* rowmax = colmax + W;     // H floats

    hipLaunchKernelGGL(colscan_k, dim3(W), dim3(512), 0, stream, masks, d1, colmax);
    hipLaunchKernelGGL(rowpass_k, dim3(H), dim3(512), 0, stream, d1, out, rowmax);
    hipLaunchKernelGGL(finalize_k, dim3(H), dim3(512), 0, stream, masks, colmax, rowmax, out);
}